// Round 9
// baseline (716.071 us; speedup 1.0000x reference)
//
#include <hip/hip_runtime.h>

// ---------------- common helpers ----------------
typedef unsigned short ushortT;
typedef unsigned int uint32;
typedef __attribute__((ext_vector_type(8))) short short8;
typedef __attribute__((ext_vector_type(4))) float f32x4;

__device__ __forceinline__ ushortT f2bf(float f) {
    uint32 u = __float_as_uint(f);
    uint32 r = (u + 0x7fffu + ((u >> 16) & 1u)) >> 16;
    return (ushortT)r;
}
__device__ __forceinline__ float bf2f(uint32 v) {
    return __uint_as_float(v << 16);
}

__device__ __forceinline__ void unpack8(uint4 v, float* f) {
    f[0] = bf2f(v.x & 0xffffu); f[1] = bf2f(v.x >> 16);
    f[2] = bf2f(v.y & 0xffffu); f[3] = bf2f(v.y >> 16);
    f[4] = bf2f(v.z & 0xffffu); f[5] = bf2f(v.z >> 16);
    f[6] = bf2f(v.w & 0xffffu); f[7] = bf2f(v.w >> 16);
}

// async global->LDS, 16B per lane. LDS dest must be wave-uniform base;
// HW writes lane i at base + i*16.
typedef __attribute__((address_space(1))) const void gvoid;
typedef __attribute__((address_space(3))) void lvoid;
__device__ __forceinline__ void gld16(const ushortT* g, ushortT* l) {
    __builtin_amdgcn_global_load_lds((gvoid*)g, (lvoid*)l, 16, 0, 0);
}

// ---------------- fp32 -> bf16 convert: x (activation) ----------------
__global__ __launch_bounds__(256) void f32_to_bf16_kernel(
    const float* __restrict__ src, ushortT* __restrict__ dst, int n4)
{
    int i = blockIdx.x * 256 + threadIdx.x;
    if (i < n4) {
        float4 v = reinterpret_cast<const float4*>(src)[i];
        ushort4 o;
        o.x = f2bf(v.x); o.y = f2bf(v.y); o.z = f2bf(v.z); o.w = f2bf(v.w);
        reinterpret_cast<ushort4*>(dst)[i] = o;
    }
}

// ---------------- all 4 weight matrices -> one contiguous bf16 buffer ----
__global__ __launch_bounds__(256) void wconv_kernel(
    const float* __restrict__ s0, const float* __restrict__ s1,
    const float* __restrict__ s2, const float* __restrict__ s3,
    ushortT* __restrict__ dst)
{
    int i = blockIdx.x * 256 + threadIdx.x;      // 0 .. 4*262144-1
    const int wsel = i >> 18;
    const int off  = i & 262143;
    const float* s = (wsel == 0) ? s0 : (wsel == 1 ? s1 : (wsel == 2 ? s2 : s3));
    float4 v = reinterpret_cast<const float4*>(s)[off];
    ushort4 o;
    o.x = f2bf(v.x); o.y = f2bf(v.y); o.z = f2bf(v.z); o.w = f2bf(v.w);
    reinterpret_cast<ushort4*>(dst)[i] = o;
}

// ---------------- pack q/k/v biases into one 3072-float buffer ----------------
__global__ __launch_bounds__(256) void pack_bias_kernel(
    const float* __restrict__ bq, const float* __restrict__ bk,
    const float* __restrict__ bv, float* __restrict__ out)
{
    int i = blockIdx.x * 256 + threadIdx.x;   // 3072
    float v = (i < 1024) ? bq[i] : (i < 2048 ? bk[i - 1024] : bv[i - 2048]);
    out[i] = v;
}

// ---------------- RoPE cos/sin table: [T][16] float2 ----------------
__global__ __launch_bounds__(256) void rope_table_kernel(float2* __restrict__ tab)
{
    int idx = blockIdx.x * 256 + threadIdx.x;   // T*16 = 131072 entries
    int t = idx >> 4;
    int i = idx & 15;
    float inv = powf(10000.0f, -(float)i / 16.0f);
    float ang = (float)t * inv;
    tab[idx] = make_float2(cosf(ang), sinf(ang));
}

// swizzled LDS fragment read: region has 32-col rows; e ^= ((row>>1)&3)<<3
__device__ __forceinline__ short8 ldsfrag(const ushortT* region, int row, int g) {
    int e = (row << 5) + (g << 3);
    e ^= ((row >> 1) & 3) << 3;
    return *reinterpret_cast<const short8*>(region + e);
}

#define MC_ ((size_t)33554432)   // 32768 * 1024

// ---------------- merged-projection qkv GEMM ----------------
// r8 post-mortem: 3 schedules all ~22% MfmaUtil. Per-wave per-tile chain was
// 8 ds_read (96cy) + 16 MFMA (78cy) + barrier -> duty cycle <=25% no matter
// the sync style; ~10 waves/CU caps every pipe at ~22%. Fix: one block
// computes q,k,v for its tile: A staged ONCE for 3 projections; per tile per
// wave: 10 ds_read (120cy) vs 24 MFMA (116cy) burst; prologue+epilogue
// amortized 3x. Block = 128 rows x 64 cols (per proj), 4 waves (wm,wn in
// {0,1}), wave-tile 64x32 per proj, acc[3][4][2] f32x4 = 96 VGPR.
// LDS buffer = A(128x32=8KB) + 3x B(64x32=4KB) = 20KB; double-buffered 40KB.
// Schedule: r7-proven syncthreads-per-tile (drains vmcnt+lgkm), STAGE next
// tile right after barrier.
// XCD co-location: xi=bid&7, j=bid>>3; tn=j&15, tm=xi*32+(j>>4).
// Epilogue per proj: q: rope->bf16; k/v: fp32 present (pre-rope, (B,H,T,64))
// + rope->bf16.
__global__ __launch_bounds__(256, 2) void gemm_qkv_kernel(
    const ushortT* __restrict__ A,      // M x K bf16
    const ushortT* __restrict__ Wall,   // [wq;wk;wv] (3*1024 x K)
    const float*   __restrict__ biasAll,// 3072
    const float2*  __restrict__ tab,    // rope table [T][16]
    ushortT*       __restrict__ CbAll,  // qlin (klin=+MC, vlin=+2MC)
    float*         __restrict__ CfAll,  // presK (presV=+MC)
    int M, int K)
{
    __shared__ ushortT lds[2 * 10240];   // 2 bufs x 20KB = 40KB
    const int tid  = threadIdx.x;
    const int lane = tid & 63;
    const int wv   = tid >> 6;        // 0..3
    const int wm   = wv >> 1;         // 0..1  (64-row half)
    const int wn   = wv & 1;          // 0..1  (32-col half)
    const int g    = lane >> 4;       // k sub-block 0..3 (also C/D row group)
    const int rsel = lane & 15;

    // XCD co-location: 4096 blocks = 8 xcd x (32 tm x 16 tn)
    const int bid = blockIdx.x;
    const int xi  = bid & 7;
    const int j   = bid >> 3;
    const int tn  = j & 15;
    const int tm  = xi * 32 + (j >> 4);
    const int m0  = tm * 128, n0 = tn * 64;

    // staging source: chunk c -> row c>>2, col8 = (c&3)^((c>>3)&3)
    const int crow = tid >> 2;                       // 0..63
    const int ccol = ((tid & 3) ^ ((tid >> 3) & 3)) * 8;
    const ushortT* gA0 = A + (size_t)(m0 + crow) * K + ccol;
    const ushortT* gA1 = gA0 + (size_t)64 * K;       // rows +64
    const ushortT* gBq = Wall + (size_t)(n0 + crow) * K + ccol;
    const ushortT* gBk = gBq + (size_t)1024 * K;
    const ushortT* gBv = gBq + (size_t)2048 * K;

    // wave-uniform LDS dest bases (ushort offsets within a buffer)
    const int dA0 = wv * 512;           // A rows 0..63
    const int dA1 = 2048 + wv * 512;    // A rows 64..127
    const int dB  = wv * 512;           // within each 2048-elem B region

    #define STAGE(buf, t) { \
        ushortT* b_ = lds + (buf) * 10240; \
        gld16(gA0 + (t) * 32, b_ + dA0); \
        gld16(gA1 + (t) * 32, b_ + dA1); \
        gld16(gBq + (t) * 32, b_ + 4096 + dB); \
        gld16(gBk + (t) * 32, b_ + 6144 + dB); \
        gld16(gBv + (t) * 32, b_ + 8192 + dB); \
    }

    f32x4 acc[3][4][2] = {};
    const int NT = K >> 5;   // 32 K-tiles
    int cur = 0;

    STAGE(0, 0);

    #pragma unroll 1
    for (int t = 0; t < NT; ++t) {
        __syncthreads();   // drains vmcnt+lgkm: buf[cur] staged, prior reads done
        if (t + 1 < NT) STAGE(cur ^ 1, t + 1);

        const ushortT* bb = lds + cur * 10240;
        short8 Af[4], Bf[3][2];
        #pragma unroll
        for (int fm = 0; fm < 4; ++fm)
            Af[fm] = ldsfrag(bb, wm * 64 + fm * 16 + rsel, g);
        #pragma unroll
        for (int p = 0; p < 3; ++p)
            #pragma unroll
            for (int fn = 0; fn < 2; ++fn)
                Bf[p][fn] = ldsfrag(bb + 4096 + p * 2048, wn * 32 + fn * 16 + rsel, g);

        #pragma unroll
        for (int p = 0; p < 3; ++p)
            #pragma unroll
            for (int fm = 0; fm < 4; ++fm)
                #pragma unroll
                for (int fn = 0; fn < 2; ++fn)
                    acc[p][fm][fn] = __builtin_amdgcn_mfma_f32_16x16x32_bf16(
                        Af[fm], Bf[p][fn], acc[p][fm][fn], 0, 0, 0);
        cur ^= 1;
    }
    #undef STAGE

    // epilogue: C/D layout col = rsel, row = g*4 + e (within 16x16 frag)
    #pragma unroll
    for (int p = 0; p < 3; ++p) {
        #pragma unroll
        for (int fn = 0; fn < 2; ++fn) {
            const int colb = n0 + wn * 32 + fn * 16 + rsel;   // 0..1023
            const int d    = colb & 63;
            const float bv = biasAll[p * 1024 + colb];
            #pragma unroll
            for (int fm = 0; fm < 4; ++fm) {
                const int rowbase = m0 + wm * 64 + fm * 16 + g * 4;
                #pragma unroll
                for (int e = 0; e < 4; ++e) {
                    const int row = rowbase + e;
                    const float val = acc[p][fm][fn][e] + bv;
                    if (p != 0) {
                        // present: (B, H, T, 64) fp32, pre-rope
                        const int b = row >> 13, t = row & 8191;
                        const int h = colb >> 6;
                        CfAll[(size_t)(p - 1) * MC_ +
                              (((size_t)b * 16 + h) * 8192 + t) * 64 + d] = val;
                    }
                    // rope: pair (d, d^1) sits at lane^1, same row
                    const float pv = __shfl_xor(val, 1, 64);
                    float ov = val;
                    if (d < 32) {
                        const int t = row & 8191;
                        const float2 cs = tab[t * 16 + (d >> 1)];
                        ov = (d & 1) ? fmaf(val, cs.x,  pv * cs.y)
                                     : fmaf(val, cs.x, -pv * cs.y);
                    }
                    CbAll[(size_t)p * MC_ + (size_t)row * 1024 + colb] = f2bf(ov);
                }
            }
        }
    }
}

// ---------------- output projection GEMM (fp32 out, no rope) ----------------
// 128x128 tile, 4 waves 2m x 2n, wave 64x64 = 4x4 frags, BK=32, 2 bufs 32KB
// -> 4+ blocks/CU. syncthreads-per-tile schedule. Renamed for rocprof.
__global__ __launch_bounds__(256, 4) void gemm_out_kernel(
    const ushortT* __restrict__ A,    // M x K bf16
    const ushortT* __restrict__ W,    // 1024 x K bf16
    const float*   __restrict__ bias,
    float*         __restrict__ Cf,   // M x N fp32
    int M, int N, int K)
{
    __shared__ ushortT lds[2 * 8192];   // 2 bufs x (A 4096 + B 4096) = 32KB
    const int tid  = threadIdx.x;
    const int lane = tid & 63;
    const int wv   = tid >> 6;
    const int wm   = wv >> 1;
    const int wn   = wv & 1;
    const int g    = lane >> 4;
    const int rsel = lane & 15;

    // XCD co-location: 2048 blocks = 8 xcd x (32 tm x 8 tn)
    const int bid = blockIdx.x;
    const int xi  = bid & 7;
    const int j   = bid >> 3;
    const int tn  = j & 7;
    const int tm  = xi * 32 + (j >> 3);
    const int m0  = tm * 128, n0 = tn * 128;

    const int crow = tid >> 2;
    const int ccol = ((tid & 3) ^ ((tid >> 3) & 3)) * 8;
    const ushortT* gA0 = A + (size_t)(m0 + crow) * K + ccol;
    const ushortT* gA1 = gA0 + (size_t)64 * K;
    const ushortT* gB0 = W + (size_t)(n0 + crow) * K + ccol;
    const ushortT* gB1 = gB0 + (size_t)64 * K;

    const int dst0 = wv * 512;
    const int dst1 = 2048 + wv * 512;

    #define STAGE(buf, t) { \
        ushortT* b_ = lds + (buf) * 8192; \
        gld16(gA0 + (t) * 32, b_ + dst0); \
        gld16(gA1 + (t) * 32, b_ + dst1); \
        gld16(gB0 + (t) * 32, b_ + 4096 + dst0); \
        gld16(gB1 + (t) * 32, b_ + 4096 + dst1); \
    }

    f32x4 acc[4][4] = {};
    const int NT = K >> 5;
    int cur = 0;

    STAGE(0, 0);

    #pragma unroll 1
    for (int t = 0; t < NT; ++t) {
        __syncthreads();
        if (t + 1 < NT) STAGE(cur ^ 1, t + 1);

        const ushortT* ra = lds + cur * 8192;
        const ushortT* rb = ra + 4096;
        short8 Af[4], Bf[4];
        #pragma unroll
        for (int fm = 0; fm < 4; ++fm) Af[fm] = ldsfrag(ra, wm * 64 + fm * 16 + rsel, g);
        #pragma unroll
        for (int fn = 0; fn < 4; ++fn) Bf[fn] = ldsfrag(rb, wn * 64 + fn * 16 + rsel, g);
        #pragma unroll
        for (int fm = 0; fm < 4; ++fm)
            #pragma unroll
            for (int fn = 0; fn < 4; ++fn)
                acc[fm][fn] = __builtin_amdgcn_mfma_f32_16x16x32_bf16(Af[fm], Bf[fn], acc[fm][fn], 0, 0, 0);
        cur ^= 1;
    }
    #undef STAGE

    #pragma unroll
    for (int fn = 0; fn < 4; ++fn) {
        const int colb = n0 + wn * 64 + fn * 16 + rsel;
        const float bv = bias[colb];
        #pragma unroll
        for (int fm = 0; fm < 4; ++fm) {
            const int rowbase = m0 + wm * 64 + fm * 16 + g * 4;
            #pragma unroll
            for (int e = 0; e < 4; ++e) {
                const int row = rowbase + e;
                Cf[(size_t)row * N + colb] = acc[fm][fn][e] + bv;
            }
        }
    }
}

// ---------------- neighborhood attention ----------------
// wave = 8 queries x 8 dim-chunks; lane = tloc*8 + c  (8 consecutive lanes
// cover one contiguous 128B row segment). q/k/v already roped.
__global__ __launch_bounds__(256) void natt_kernel(
    const ushortT* __restrict__ Q,
    const ushortT* __restrict__ Kl,
    const ushortT* __restrict__ Vl,
    ushortT*       __restrict__ O)
{
    const int T = 8192;
    const int tid  = threadIdx.x;
    const int lane = tid & 63;
    const int tloc = lane >> 3;
    const int c    = lane & 7;

    const int wq   = (blockIdx.x * 256 + tid) >> 6;  // wave-group id
    const int qidx = wq * 8 + tloc;
    const int t = qidx & (T - 1);
    const int h = (qidx >> 13) & 15;
    const int b = qidx >> 17;

    const int shifts[4] = {0, 2, 3, 4};
    const int sh = shifts[h >> 2];
    const int dd = 1 << sh;

    const int r  = t & (dd - 1);
    const int p  = t >> sh;
    const int Lr = ((T - 1 - r) >> sh) + 1;
    int s = p - 3;
    const int smax = Lr - 7;
    s = s < 0 ? 0 : (s > smax ? smax : s);
    const int tbase = r + (s << sh);

    const size_t qoff = ((size_t)(b * T + t)) * 1024 + h * 64 + c * 8;
    float qf[8];
    unpack8(*reinterpret_cast<const uint4*>(Q + qoff), qf);

    const size_t cbase = ((size_t)b * T) * 1024 + h * 64 + c * 8;

    float sc[7];
    #pragma unroll
    for (int j = 0; j < 7; ++j) {
        const int tj = tbase + (j << sh);
        float kf[8];
        unpack8(*reinterpret_cast<const uint4*>(Kl + cbase + (size_t)tj * 1024), kf);
        float pp = 0.f;
        #pragma unroll
        for (int i = 0; i < 8; ++i) pp = fmaf(qf[i], kf[i], pp);
        pp += __shfl_xor(pp, 1, 64);
        pp += __shfl_xor(pp, 2, 64);
        pp += __shfl_xor(pp, 4, 64);
        sc[j] = pp;
    }

    float mx = sc[0];
    #pragma unroll
    for (int j = 1; j < 7; ++j) mx = fmaxf(mx, sc[j]);
    float den = 0.f;
    #pragma unroll
    for (int j = 0; j < 7; ++j) { sc[j] = __expf(sc[j] - mx); den += sc[j]; }
    const float inv = 1.0f / den;

    float out[8] = {};
    #pragma unroll
    for (int j = 0; j < 7; ++j) {
        const int tj = tbase + (j << sh);
        float vf[8];
        unpack8(*reinterpret_cast<const uint4*>(Vl + cbase + (size_t)tj * 1024), vf);
        #pragma unroll
        for (int i = 0; i < 8; ++i) out[i] = fmaf(sc[j], vf[i], out[i]);
    }

    short8 ov;
    #pragma unroll
    for (int i = 0; i < 8; ++i) ov[i] = (short)f2bf(out[i] * inv);
    *reinterpret_cast<short8*>(const_cast<ushortT*>(O + qoff)) = ov;
}

// ---------------- launcher ----------------
extern "C" void kernel_launch(void* const* d_in, const int* in_sizes, int n_in,
                              void* d_out, int out_size, void* d_ws, size_t ws_size,
                              hipStream_t stream)
{
    const float* x  = (const float*)d_in[0];
    const float* wq = (const float*)d_in[1];
    const float* bq = (const float*)d_in[2];
    const float* wk = (const float*)d_in[3];
    const float* bk = (const float*)d_in[4];
    const float* wv = (const float*)d_in[5];
    const float* bv = (const float*)d_in[6];
    const float* wp = (const float*)d_in[7];
    const float* bp = (const float*)d_in[8];

    const int B = 4, T = 8192, C = 1024;
    const int M = B * T;                    // 32768
    const size_t MC = (size_t)M * C;        // 33,554,432

    char* ws = (char*)d_ws;
    ushortT* xb    = (ushortT*)ws;                                  // 64MB (reused as attn out)
    ushortT* wallb = (ushortT*)(ws + (size_t)64 * 1024 * 1024);     // 8MB: [wq][wk][wv][wp]
    ushortT* wpb   = wallb + (size_t)3 * C * C;
    ushortT* qlin  = (ushortT*)(ws + (size_t)72 * 1024 * 1024);     // 64MB (klin,vlin follow)
    ushortT* klin  = qlin + MC;
    ushortT* vlin  = klin + MC;
    float2*  tab   = (float2*)(ws + (size_t)264 * 1024 * 1024);     // 1MB
    float*   bqkv  = (float*)(ws + (size_t)266 * 1024 * 1024);      // 12KB

    float* y     = (float*)d_out;
    float* presK = y + MC;                  // presV = presK + MC (contiguous)

    rope_table_kernel<<<512, 256, 0, stream>>>(tab);
    pack_bias_kernel<<<12, 256, 0, stream>>>(bq, bk, bv, bqkv);

    f32_to_bf16_kernel<<<(int)(MC / 4 / 256), 256, 0, stream>>>(x, xb, (int)(MC / 4));
    wconv_kernel<<<4 * (C * C / 4) / 256, 256, 0, stream>>>(wq, wk, wv, wp, wallb);

    // merged qkv: grid 4096 (128-row x 64-col tiles, 3 projections per block)
    gemm_qkv_kernel<<<4096, 256, 0, stream>>>(
        xb, wallb, bqkv, tab, qlin, presK, M, C);

    natt_kernel<<<(B * 16 * T) / 32, 256, 0, stream>>>(qlin, klin, vlin, xb);

    // output projection: grid 2048
    gemm_out_kernel<<<2048, 256, 0, stream>>>(
        xb, wpb, bp, y, M, C, C);
}

// Round 10
// 573.205 us; speedup vs baseline: 1.2492x; 1.2492x over previous
//
#include <hip/hip_runtime.h>

// ---------------- common helpers ----------------
typedef unsigned short ushortT;
typedef unsigned int uint32;
typedef __attribute__((ext_vector_type(8))) short short8;
typedef __attribute__((ext_vector_type(4))) float f32x4;

__device__ __forceinline__ ushortT f2bf(float f) {
    uint32 u = __float_as_uint(f);
    uint32 r = (u + 0x7fffu + ((u >> 16) & 1u)) >> 16;
    return (ushortT)r;
}
__device__ __forceinline__ float bf2f(uint32 v) {
    return __uint_as_float(v << 16);
}

__device__ __forceinline__ void unpack8(uint4 v, float* f) {
    f[0] = bf2f(v.x & 0xffffu); f[1] = bf2f(v.x >> 16);
    f[2] = bf2f(v.y & 0xffffu); f[3] = bf2f(v.y >> 16);
    f[4] = bf2f(v.z & 0xffffu); f[5] = bf2f(v.z >> 16);
    f[6] = bf2f(v.w & 0xffffu); f[7] = bf2f(v.w >> 16);
}

// async global->LDS, 16B per lane. LDS dest must be wave-uniform base;
// HW writes lane i at base + i*16.
typedef __attribute__((address_space(1))) const void gvoid;
typedef __attribute__((address_space(3))) void lvoid;
__device__ __forceinline__ void gld16(const ushortT* g, ushortT* l) {
    __builtin_amdgcn_global_load_lds((gvoid*)g, (lvoid*)l, 16, 0, 0);
}

// ---------------- fp32 -> bf16 convert: x (activation) ----------------
__global__ __launch_bounds__(256) void f32_to_bf16_kernel(
    const float* __restrict__ src, ushortT* __restrict__ dst, int n4)
{
    int i = blockIdx.x * 256 + threadIdx.x;
    if (i < n4) {
        float4 v = reinterpret_cast<const float4*>(src)[i];
        ushort4 o;
        o.x = f2bf(v.x); o.y = f2bf(v.y); o.z = f2bf(v.z); o.w = f2bf(v.w);
        reinterpret_cast<ushort4*>(dst)[i] = o;
    }
}

// ---------------- all 4 weight matrices -> one contiguous bf16 buffer ----
__global__ __launch_bounds__(256) void wconv_kernel(
    const float* __restrict__ s0, const float* __restrict__ s1,
    const float* __restrict__ s2, const float* __restrict__ s3,
    ushortT* __restrict__ dst)
{
    int i = blockIdx.x * 256 + threadIdx.x;      // 0 .. 4*262144-1
    const int wsel = i >> 18;
    const int off  = i & 262143;
    const float* s = (wsel == 0) ? s0 : (wsel == 1 ? s1 : (wsel == 2 ? s2 : s3));
    float4 v = reinterpret_cast<const float4*>(s)[off];
    ushort4 o;
    o.x = f2bf(v.x); o.y = f2bf(v.y); o.z = f2bf(v.z); o.w = f2bf(v.w);
    reinterpret_cast<ushort4*>(dst)[i] = o;
}

// ---------------- pack q/k/v biases into one 3072-float buffer ----------------
__global__ __launch_bounds__(256) void pack_bias_kernel(
    const float* __restrict__ bq, const float* __restrict__ bk,
    const float* __restrict__ bv, float* __restrict__ out)
{
    int i = blockIdx.x * 256 + threadIdx.x;   // 3072
    float v = (i < 1024) ? bq[i] : (i < 2048 ? bk[i - 1024] : bv[i - 2048]);
    out[i] = v;
}

// ---------------- RoPE cos/sin table: [T][16] float2 ----------------
__global__ __launch_bounds__(256) void rope_table_kernel(float2* __restrict__ tab)
{
    int idx = blockIdx.x * 256 + threadIdx.x;   // T*16 = 131072 entries
    int t = idx >> 4;
    int i = idx & 15;
    float inv = powf(10000.0f, -(float)i / 16.0f);
    float ang = (float)t * inv;
    tab[idx] = make_float2(cosf(ang), sinf(ang));
}

// swizzled LDS fragment read: region has 32-col rows; e ^= ((row>>1)&3)<<3
__device__ __forceinline__ short8 ldsfrag(const ushortT* region, int row, int g) {
    int e = (row << 5) + (g << 3);
    e ^= ((row >> 1) & 3) << 3;
    return *reinterpret_cast<const short8*>(region + e);
}

#define MC_ ((size_t)33554432)   // 32768 * 1024

// ---------------- 256x128-tile bf16 MFMA GEMM ----------------
// r9 post-mortem: (a) merged-proj broke the 2MB/XCD weight budget (FETCH
// 412MB, r4 failure repeated) -- separate projections forever. (b) The
// ~22-24% MfmaUtil wall across 3 schedules is L2->LDS BANDWIDTH: 128x128
// tiles demand ~53 B/cy/CU staged at full MFMA rate = the L2 ceiling.
// Fix: 256x128 tile = 87 FLOP/staged-byte (vs 64). Per-wave work identical
// to the m97 shape (acc[4][4], 8 ds_read, 16 MFMA, ~80 VGPR) -> 512 thr,
// 8 waves (4m x 2n); LDS 2 x 24KB = 48KB -> 2-3 blocks/CU, 16+ waves/CU.
// Per-CU staged demand at full MFMA drops to ~40 B/cy < achieved L2.
// Schedule: syncthreads-per-tile (r7==r8 showed sync style is not the lever).
//
// XCD co-location: per proj-phase 1024 blocks = 8 xcd x (16 tm x 8 tn);
// xi=bid&7, j=bid>>3; tn=j&7 (fastest: 8 tn-blocks share an A panel),
// tm=xi*16+(j>>3). W per phase = 2MB (fits L2 beside A panels).
//
// MODE 3: merged qkv dispatch, grid 3072; proj = bid>>10 in {0,1,2}
//   (phases sequential -> W footprint 2MB at a time).
//   proj 0 (q): rope -> bf16; proj 1/2 (k/v): fp32 present (pre-rope,
//   (B,H,T,64)) + rope -> bf16.
// MODE 2: fp32 out, no rope (final projection), grid 1024.
template<int MODE>
__global__ __launch_bounds__(512, 4) void gemm_wide_kernel(
    const ushortT* __restrict__ A,    // M x K bf16
    const ushortT* __restrict__ Wall, // MODE3: [wq;wk;wv] (3*1024 x K); MODE2: 1024 x K
    const float*   __restrict__ biasAll, // MODE3: 3072; MODE2: 1024
    const float2*  __restrict__ tab,  // rope table [T][16]
    ushortT*       __restrict__ CbAll,// MODE3: qlin (klin=+MC, vlin=+2MC)
    float*         __restrict__ CfAll,// MODE3: presK (presV=+MC); MODE2: MxN fp32
    int M, int N, int K)
{
    __shared__ ushortT lds[2 * 12288];  // 2 bufs x (A 8192 + B 4096) elems = 48 KB
    const int tid  = threadIdx.x;
    const int lane = tid & 63;
    const int wv   = tid >> 6;        // 0..7
    const int wm   = wv >> 1;         // 0..3  (64-row quarter of 256)
    const int wn   = wv & 1;          // 0..1  (64-col half of 128)
    const int g    = lane >> 4;       // k sub-block 0..3 (also C/D row group)
    const int rsel = lane & 15;

    // projection select (MODE 3) + per-projection block id
    const int bidAll = blockIdx.x;
    const int proj   = (MODE == 3) ? (bidAll >> 10) : 0;
    const int bid    = (MODE == 3) ? (bidAll & 1023) : bidAll;

    const ushortT* W    = Wall + (size_t)proj * 1024 * K;
    const float*   bias = biasAll + proj * 1024;

    // XCD co-location: 1024 blocks = 8 xcd x (16 tm x 8 tn)
    const int xi  = bid & 7;
    const int j   = bid >> 3;
    const int tn  = j & 7;
    const int tm  = xi * 16 + (j >> 3);
    const int m0  = tm * 256, n0 = tn * 128;

    // staging source: chunk c -> row c>>2, col8 = (c&3)^((c>>3)&3)
    // (pre-swizzled global source; LDS dest stays linear: chunk*16B)
    const int crow = tid >> 2;                       // 0..127
    const int ccol = ((tid & 3) ^ ((tid >> 3) & 3)) * 8;
    const ushortT* gA0 = A + (size_t)(m0 + crow) * K + ccol;   // A rows 0..127
    const ushortT* gA1 = gA0 + (size_t)128 * K;                // A rows 128..255
    const ushortT* gB0 = W + (size_t)(n0 + crow) * K + ccol;   // B rows 0..127

    // wave-uniform LDS dest bases (element offsets within a 12288-elem buffer)
    const int dA0 = wv * 512;           // A chunks tid       (rows 0..127)
    const int dA1 = 4096 + wv * 512;    // A chunks tid+512   (rows 128..255)
    const int dB  = 8192 + wv * 512;    // B chunks tid       (rows 0..127)

    #define STAGE(buf, t) { \
        ushortT* b_ = lds + (buf) * 12288; \
        gld16(gA0 + (t) * 32, b_ + dA0); \
        gld16(gA1 + (t) * 32, b_ + dA1); \
        gld16(gB0 + (t) * 32, b_ + dB); \
    }

    f32x4 acc[4][4] = {};
    const int NT = K >> 5;   // 32 K-tiles
    int cur = 0;

    STAGE(0, 0);

    #pragma unroll 1
    for (int t = 0; t < NT; ++t) {
        __syncthreads();   // drains vmcnt+lgkm: buf[cur] staged, prior reads done
        if (t + 1 < NT) STAGE(cur ^ 1, t + 1);

        const ushortT* ra = lds + cur * 12288;
        const ushortT* rb = ra + 8192;
        short8 Af[4], Bf[4];
        #pragma unroll
        for (int fm = 0; fm < 4; ++fm) Af[fm] = ldsfrag(ra, wm * 64 + fm * 16 + rsel, g);
        #pragma unroll
        for (int fn = 0; fn < 4; ++fn) Bf[fn] = ldsfrag(rb, wn * 64 + fn * 16 + rsel, g);
        #pragma unroll
        for (int fm = 0; fm < 4; ++fm)
            #pragma unroll
            for (int fn = 0; fn < 4; ++fn)
                acc[fm][fn] = __builtin_amdgcn_mfma_f32_16x16x32_bf16(Af[fm], Bf[fn], acc[fm][fn], 0, 0, 0);
        cur ^= 1;
    }
    #undef STAGE

    // epilogue: C/D layout col = rsel, row = g*4 + e (within 16x16 frag)
    #pragma unroll
    for (int fn = 0; fn < 4; ++fn) {
        const int colb = n0 + wn * 64 + fn * 16 + rsel;   // 0..1023
        const int d    = colb & 63;
        const float bv = bias[colb];
        #pragma unroll
        for (int fm = 0; fm < 4; ++fm) {
            const int rowbase = m0 + wm * 64 + fm * 16 + g * 4;
            #pragma unroll
            for (int e = 0; e < 4; ++e) {
                const int row = rowbase + e;
                const float val = acc[fm][fn][e] + bv;
                if (MODE == 2) {
                    CfAll[(size_t)row * N + colb] = val;
                } else {
                    if (proj != 0) {
                        // present: (B, H, T, 64) fp32, pre-rope
                        const int b = row >> 13, t = row & 8191;
                        const int h = colb >> 6;
                        CfAll[(size_t)(proj - 1) * MC_ +
                              (((size_t)b * 16 + h) * 8192 + t) * 64 + d] = val;
                    }
                    // rope: pair (d, d^1) sits at lane^1, same row
                    const float pv = __shfl_xor(val, 1, 64);
                    float ov = val;
                    if (d < 32) {
                        const int t = row & 8191;
                        const float2 cs = tab[t * 16 + (d >> 1)];
                        ov = (d & 1) ? fmaf(val, cs.x,  pv * cs.y)
                                     : fmaf(val, cs.x, -pv * cs.y);
                    }
                    CbAll[(size_t)proj * MC_ + (size_t)row * 1024 + colb] = f2bf(ov);
                }
            }
        }
    }
}

// ---------------- neighborhood attention ----------------
// wave = 8 queries x 8 dim-chunks; lane = tloc*8 + c  (8 consecutive lanes
// cover one contiguous 128B row segment). q/k/v already roped.
__global__ __launch_bounds__(256) void natt_kernel(
    const ushortT* __restrict__ Q,
    const ushortT* __restrict__ Kl,
    const ushortT* __restrict__ Vl,
    ushortT*       __restrict__ O)
{
    const int T = 8192;
    const int tid  = threadIdx.x;
    const int lane = tid & 63;
    const int tloc = lane >> 3;
    const int c    = lane & 7;

    const int wq   = (blockIdx.x * 256 + tid) >> 6;  // wave-group id
    const int qidx = wq * 8 + tloc;
    const int t = qidx & (T - 1);
    const int h = (qidx >> 13) & 15;
    const int b = qidx >> 17;

    const int shifts[4] = {0, 2, 3, 4};
    const int sh = shifts[h >> 2];
    const int dd = 1 << sh;

    const int r  = t & (dd - 1);
    const int p  = t >> sh;
    const int Lr = ((T - 1 - r) >> sh) + 1;
    int s = p - 3;
    const int smax = Lr - 7;
    s = s < 0 ? 0 : (s > smax ? smax : s);
    const int tbase = r + (s << sh);

    const size_t qoff = ((size_t)(b * T + t)) * 1024 + h * 64 + c * 8;
    float qf[8];
    unpack8(*reinterpret_cast<const uint4*>(Q + qoff), qf);

    const size_t cbase = ((size_t)b * T) * 1024 + h * 64 + c * 8;

    float sc[7];
    #pragma unroll
    for (int j = 0; j < 7; ++j) {
        const int tj = tbase + (j << sh);
        float kf[8];
        unpack8(*reinterpret_cast<const uint4*>(Kl + cbase + (size_t)tj * 1024), kf);
        float pp = 0.f;
        #pragma unroll
        for (int i = 0; i < 8; ++i) pp = fmaf(qf[i], kf[i], pp);
        pp += __shfl_xor(pp, 1, 64);
        pp += __shfl_xor(pp, 2, 64);
        pp += __shfl_xor(pp, 4, 64);
        sc[j] = pp;
    }

    float mx = sc[0];
    #pragma unroll
    for (int j = 1; j < 7; ++j) mx = fmaxf(mx, sc[j]);
    float den = 0.f;
    #pragma unroll
    for (int j = 0; j < 7; ++j) { sc[j] = __expf(sc[j] - mx); den += sc[j]; }
    const float inv = 1.0f / den;

    float out[8] = {};
    #pragma unroll
    for (int j = 0; j < 7; ++j) {
        const int tj = tbase + (j << sh);
        float vf[8];
        unpack8(*reinterpret_cast<const uint4*>(Vl + cbase + (size_t)tj * 1024), vf);
        #pragma unroll
        for (int i = 0; i < 8; ++i) out[i] = fmaf(sc[j], vf[i], out[i]);
    }

    short8 ov;
    #pragma unroll
    for (int i = 0; i < 8; ++i) ov[i] = (short)f2bf(out[i] * inv);
    *reinterpret_cast<short8*>(const_cast<ushortT*>(O + qoff)) = ov;
}

// ---------------- launcher ----------------
extern "C" void kernel_launch(void* const* d_in, const int* in_sizes, int n_in,
                              void* d_out, int out_size, void* d_ws, size_t ws_size,
                              hipStream_t stream)
{
    const float* x  = (const float*)d_in[0];
    const float* wq = (const float*)d_in[1];
    const float* bq = (const float*)d_in[2];
    const float* wk = (const float*)d_in[3];
    const float* bk = (const float*)d_in[4];
    const float* wv = (const float*)d_in[5];
    const float* bv = (const float*)d_in[6];
    const float* wp = (const float*)d_in[7];
    const float* bp = (const float*)d_in[8];

    const int B = 4, T = 8192, C = 1024;
    const int M = B * T;                    // 32768
    const size_t MC = (size_t)M * C;        // 33,554,432

    char* ws = (char*)d_ws;
    ushortT* xb    = (ushortT*)ws;                                  // 64MB (reused as attn out)
    ushortT* wallb = (ushortT*)(ws + (size_t)64 * 1024 * 1024);     // 8MB: [wq][wk][wv][wp]
    ushortT* wpb   = wallb + (size_t)3 * C * C;
    ushortT* qlin  = (ushortT*)(ws + (size_t)72 * 1024 * 1024);     // 64MB (klin,vlin follow)
    ushortT* klin  = qlin + MC;
    ushortT* vlin  = klin + MC;
    float2*  tab   = (float2*)(ws + (size_t)264 * 1024 * 1024);     // 1MB
    float*   bqkv  = (float*)(ws + (size_t)266 * 1024 * 1024);      // 12KB

    float* y     = (float*)d_out;
    float* presK = y + MC;                  // presV = presK + MC (contiguous)

    rope_table_kernel<<<512, 256, 0, stream>>>(tab);
    pack_bias_kernel<<<12, 256, 0, stream>>>(bq, bk, bv, bqkv);

    f32_to_bf16_kernel<<<(int)(MC / 4 / 256), 256, 0, stream>>>(x, xb, (int)(MC / 4));
    wconv_kernel<<<4 * (C * C / 4) / 256, 256, 0, stream>>>(wq, wk, wv, wp, wallb);

    // merged qkv dispatch: grid 3072 = 3 proj x 1024 blocks (256x128 tiles)
    gemm_wide_kernel<3><<<3072, 512, 0, stream>>>(
        xb, wallb, bqkv, tab, qlin, presK, M, C, C);

    natt_kernel<<<(B * 16 * T) / 32, 256, 0, stream>>>(qlin, klin, vlin, xb);

    // output projection: grid 1024
    gemm_wide_kernel<2><<<1024, 512, 0, stream>>>(
        xb, wpb, bp, tab, nullptr, y, M, C, C);
}